// Round 7
// baseline (316.420 us; speedup 1.0000x reference)
//
#include <hip/hip_runtime.h>
#include <stdint.h>

// MatrixKAN as dense bf16 MFMA GEMM over expanded interpolation basis.
// Per feature slots [0..20]=hat (2 nonzero), 21=silu(xc) (pairs base_w), 22..23=pad.
// K = 512*24 = 12288. Plane-major LDS tiles (plane = 16B chunk column of 128 rows,
// stride 2048B): conflict-free for linear global_load_lds DMA, lane-linear A
// ds_writes, and 16-row frag reads (R6-verified: SQ_LDS_BANK_CONFLICT = 0).
// BK=96 (4 features, 12 chunks, 3 K32-steps), 48KB LDS -> 3 blocks/CU.
// R7: KSPLIT=3 (768 blocks = exactly 3/CU, single packed round, no tail) and
// split-K reduction fused into the GEMM via per-tile ticket atomics (last
// arriving z-block sums partials and writes out) -- reduce kernel removed.

typedef short v8s __attribute__((ext_vector_type(8)));
typedef float v4f __attribute__((ext_vector_type(4)));

#define B_DIM 8192
#define IN_DIM 512
#define OUT_DIM 512
#define G_DIM 20
#define FPT 4                        // features per K-tile
#define KT_TOTAL (IN_DIM / FPT)      // 128 K-tiles
#define KSPLIT 3
#define BM 128
#define BN 128
#define CHUNKS 12                    // 16B chunks per tile-row (3 per feature)
#define PLANE 2048                   // 128 rows * 16B per chunk-plane
#define TILE_BYTES (CHUNKS * PLANE)  // 24 KB
#define NTILES ((B_DIM / BM) * (OUT_DIM / BN))   // 256

#define P_BYTES ((size_t)IN_DIM * B_DIM * 8)                          // 33.55 MB
#define WT_BYTES ((size_t)(OUT_DIM / BN) * KT_TOTAL * TILE_BYTES)     // 12.58 MB
#define PART_ELEMS ((size_t)B_DIM * OUT_DIM)
#define WS_NEED (P_BYTES + WT_BYTES + (size_t)KSPLIT * PART_ELEMS * 4 + NTILES * 4)

#define PACK_BLKS ((B_DIM / 64) * (IN_DIM / 64))   // 1024
#define WPACK_BLKS ((OUT_DIM * IN_DIM) / 256)      // 1024

static __device__ __forceinline__ unsigned f2bf(float f) {
  unsigned u = __builtin_bit_cast(unsigned, f);
  return (u + 0x7fffu + ((u >> 16) & 1u)) >> 16;   // RNE bf16
}

static __device__ __forceinline__ void load16(const void* g, void* l) {
  __builtin_amdgcn_global_load_lds(
      (const __attribute__((address_space(1))) unsigned*)g,
      (__attribute__((address_space(3))) unsigned*)l, 16, 0, 0);
}

__global__ void zero_out_kernel(uint4* __restrict__ out) {
  out[(size_t)blockIdx.x * 256 + threadIdx.x] = uint4{0u, 0u, 0u, 0u};
}

// Fused input-pack. Blocks [0, PACK_BLKS): x[b][i] -> P[i][b] packed
// {.x = bf16(1-t)|bf16(t)<<16, .y = idx|bf16(silu)<<16} via LDS transpose.
// Blocks [PACK_BLKS, +WPACK_BLKS): coeffs/base_w -> Wt plane-major 24KB slabs
// (slab (n_blk,kt): plane 3f+cf = slots 8cf..8cf+7 of feature kt*4+f, row=o&127),
// plus zeroing the 256 split-K tickets (stream-ordered before kan_gemm).
__global__ void pack_fused_kernel(const float* __restrict__ x, uint2* __restrict__ P,
                                  const float* __restrict__ coeffs,
                                  const float* __restrict__ base_w,
                                  char* __restrict__ Wt,
                                  unsigned* __restrict__ ticket) {
  __shared__ uint2 tile[64 * 65];
  const int t = threadIdx.x;
  if (blockIdx.x < PACK_BLKS) {
    const int b0 = (blockIdx.x & (B_DIM / 64 - 1)) * 64;
    const int i0 = (blockIdx.x / (B_DIM / 64)) * 64;
    const int tr = t >> 6;
    const int tc = t & 63;
#pragma unroll
    for (int it = 0; it < 16; ++it) {
      int br = it * 4 + tr;
      float xv = x[(size_t)(b0 + br) * IN_DIM + i0 + tc];
      float xc = fminf(fmaxf(xv, -1.0f), 1.0f);
      float xg = (xc + 1.0f) * 10.0f;           // (xc+1)*0.5*G
      int idx = (int)floorf(xg);
      idx = idx < 0 ? 0 : (idx > G_DIM - 1 ? G_DIM - 1 : idx);
      float tt = xg - (float)idx;
      float sl = xc / (1.0f + __expf(-xc));     // silu(clipped x)
      uint2 pv;
      pv.x = f2bf(1.0f - tt) | (f2bf(tt) << 16);
      pv.y = (unsigned)idx | (f2bf(sl) << 16);
      tile[tc * 65 + br] = pv;
    }
    __syncthreads();
#pragma unroll
    for (int it = 0; it < 16; ++it) {
      int ir = it * 4 + tr;
      P[(size_t)(i0 + ir) * B_DIM + b0 + tc] = tile[ir * 65 + tc];
    }
  } else {
    const unsigned u = (blockIdx.x - PACK_BLKS) * 256 + t;
    if (u < NTILES) ticket[u] = 0u;
    const int s = u >> 9;            // slab = n_blk*KT_TOTAL + kt
    const int w = u & 511;
    const int row = w >> 2;          // o & 127
    const int f = w & 3;
    const int n_blk = s / KT_TOTAL;
    const int kt = s - n_blk * KT_TOTAL;
    const int o = n_blk * 128 + row;
    const int i = kt * 4 + f;
    const size_t g = (size_t)o * IN_DIM + i;
    const float* c = coeffs + g * 21;
    float cf[21];
#pragma unroll
    for (int j = 0; j < 21; ++j) cf[j] = c[j];
    float bw = base_w[g];
    unsigned d[12];
#pragma unroll
    for (int j = 0; j < 10; ++j) d[j] = f2bf(cf[2 * j]) | (f2bf(cf[2 * j + 1]) << 16);
    d[10] = f2bf(cf[20]) | (f2bf(bw) << 16);  // slots 20, 21(=base_w)
    d[11] = 0u;                               // slots 22,23 pad
    char* slab = Wt + (size_t)s * TILE_BYTES;
#pragma unroll
    for (int p = 0; p < 3; ++p)
      *(uint4*)(slab + (3 * f + p) * PLANE + row * 16) =
          uint4{d[4 * p], d[4 * p + 1], d[4 * p + 2], d[4 * p + 3]};
  }
}

// Build one feature's 24-slot strip (12 dwords) in registers, branchless.
// Slots 2q,2q+1 in dword q. Hat: w0 at idx, w1 at idx+1; silu at slot 21.
static __device__ __forceinline__ void build_strip(uint2 pv, unsigned d[12]) {
  const unsigned w0w1 = pv.x;               // idx even, idx==2q: w0|w1<<16
  const unsigned w0hi = pv.x << 16;         // idx odd,  idx==2q+1: w0 at high
  const unsigned w1lo = pv.x >> 16;         // idx+1==2q: w1 at low
  const int idx = (int)(pv.y & 0xffffu);
  const unsigned slhi = pv.y & 0xffff0000u;
#pragma unroll
  for (int q = 0; q <= 10; ++q) {
    unsigned v = 0u;
    v = (idx == 2 * q - 1) ? w1lo : v;
    v = (idx == 2 * q)     ? w0w1 : v;
    v = (idx == 2 * q + 1) ? w0hi : v;
    d[q] = v;
  }
  d[10] |= slhi;
  d[11] = 0u;
}

template <bool ATOMIC>
__global__ __launch_bounds__(256, 3) void kan_gemm(const uint2* __restrict__ P,
                                                   const char* __restrict__ Wt,
                                                   float* __restrict__ part,
                                                   float* __restrict__ out,
                                                   unsigned* __restrict__ ticket) {
  __shared__ uint4 lds4[(2 * TILE_BYTES) / 16];   // 24KB A + 24KB B (plane-major)
  __shared__ unsigned last_flag;
  char* Ab = (char*)lds4;
  char* Bb = (char*)lds4 + TILE_BYTES;
  const int t = threadIdx.x;
  const int lane = t & 63;
  const int wv = t >> 6;               // 4 waves, 2x2 grid of 64x64 tiles
  const int wm = wv >> 1, wn = wv & 1;
  const int b0 = blockIdx.x * BM;
  const int n_blk = blockIdx.y;
  const int z = blockIdx.z;
  const int kt0 = (z * KT_TOTAL) / KSPLIT;          // 0,42,85
  const int ktend = ((z + 1) * KT_TOTAL) / KSPLIT;  // 42,85,128

  v4f acc[4][4];
  const v4f z4 = {0.f, 0.f, 0.f, 0.f};
#pragma unroll
  for (int ii = 0; ii < 4; ++ii)
#pragma unroll
    for (int jj = 0; jj < 4; ++jj) acc[ii][jj] = z4;

  // A-gen: wave wv owns feature wv (planes 3wv..3wv+2); lane owns rows lane, lane+64
  uint2 pv0 = P[(size_t)(kt0 * 4 + wv) * B_DIM + b0 + lane];
  uint2 pv1 = P[(size_t)(kt0 * 4 + wv) * B_DIM + b0 + lane + 64];

  const int r16 = lane & 15;
  const int q16 = lane >> 4;

  for (int kt = kt0; kt < ktend; ++kt) {
    __syncthreads();   // previous compute done; safe to overwrite tiles

    // B tile: 24KB linear DMA (plane-major slab, lane-linear LDS dst)
    const char* wsrc = Wt + (size_t)(n_blk * KT_TOTAL + kt) * TILE_BYTES;
#pragma unroll
    for (int q = 0; q < 6; ++q)
      load16(wsrc + (q * 256 + t) * 16, Bb + (q * 256 + t) * 16);

    // prefetch next P (in flight across barrier + compute)
    const int ktn = (kt + 1 < ktend) ? kt + 1 : kt;
    uint2 pn0 = P[(size_t)(ktn * 4 + wv) * B_DIM + b0 + lane];
    uint2 pn1 = P[(size_t)(ktn * 4 + wv) * B_DIM + b0 + lane + 64];

    // build + stage 2 A strips: 3x ds_write_b128 each, lane-contiguous per instr
    unsigned d[12];
    build_strip(pv0, d);
#pragma unroll
    for (int p = 0; p < 3; ++p)
      *(uint4*)(Ab + (3 * wv + p) * PLANE + lane * 16) =
          uint4{d[4 * p], d[4 * p + 1], d[4 * p + 2], d[4 * p + 3]};
    build_strip(pv1, d);
#pragma unroll
    for (int p = 0; p < 3; ++p)
      *(uint4*)(Ab + (3 * wv + p) * PLANE + (lane + 64) * 16) =
          uint4{d[4 * p], d[4 * p + 1], d[4 * p + 2], d[4 * p + 3]};
    pv0 = pn0;
    pv1 = pn1;

    __syncthreads();   // drains DMA (vmcnt) + A writes (lgkm)

    // compute: 3 K32-steps, 16 MFMA each per wave
#pragma unroll
    for (int s = 0; s < 3; ++s) {
      const int chunk = s * 4 + q16;   // plane index; k = chunk*8 + j
      v8s af[4], bfr[4];
#pragma unroll
      for (int rm = 0; rm < 4; ++rm) {
        int row = wm * 64 + rm * 16 + r16;
        af[rm] = *(const v8s*)(Ab + chunk * PLANE + row * 16);
      }
#pragma unroll
      for (int cn = 0; cn < 4; ++cn) {
        int row = wn * 64 + cn * 16 + r16;
        bfr[cn] = *(const v8s*)(Bb + chunk * PLANE + row * 16);
      }
#pragma unroll
      for (int rm = 0; rm < 4; ++rm)
#pragma unroll
        for (int cn = 0; cn < 4; ++cn)
          acc[rm][cn] = __builtin_amdgcn_mfma_f32_16x16x32_bf16(af[rm], bfr[cn], acc[rm][cn], 0, 0, 0);
    }
  }

  // epilogue: C/D layout col=lane&15, row=(lane>>4)*4+reg (verified m89/m91)
  const int q4 = (lane >> 4) * 4;
  if (ATOMIC) {
#pragma unroll
    for (int rm = 0; rm < 4; ++rm)
#pragma unroll
      for (int cn = 0; cn < 4; ++cn)
#pragma unroll
        for (int r = 0; r < 4; ++r) {
          int row = b0 + wm * 64 + rm * 16 + q4 + r;
          int col = n_blk * BN + wn * 64 + cn * 16 + r16;
          atomicAdd(out + (size_t)row * OUT_DIM + col, acc[rm][cn][r]);
        }
    return;
  }

  // split-K ticket reduction: store partial, bump per-tile ticket; the last
  // arriving z-block sums all partials and writes out.
  float* mypart = part + (size_t)z * PART_ELEMS;
#pragma unroll
  for (int rm = 0; rm < 4; ++rm)
#pragma unroll
    for (int cn = 0; cn < 4; ++cn)
#pragma unroll
      for (int r = 0; r < 4; ++r) {
        int row = b0 + wm * 64 + rm * 16 + q4 + r;
        int col = n_blk * BN + wn * 64 + cn * 16 + r16;
        mypart[(size_t)row * OUT_DIM + col] = acc[rm][cn][r];
      }
  __threadfence();      // release: partial visible before ticket bump
  __syncthreads();      // all threads' stores done before lane-0 bumps
  if (t == 0)
    last_flag = (atomicAdd(&ticket[n_blk * (B_DIM / BM) + blockIdx.x], 1u) == KSPLIT - 1);
  __syncthreads();
  if (last_flag) {
    __threadfence();    // acquire: see partner partials
    const float* pa = part + (size_t)((z + 1) % KSPLIT) * PART_ELEMS;
    const float* pb = part + (size_t)((z + 2) % KSPLIT) * PART_ELEMS;
#pragma unroll
    for (int rm = 0; rm < 4; ++rm)
#pragma unroll
      for (int cn = 0; cn < 4; ++cn)
#pragma unroll
        for (int r = 0; r < 4; ++r) {
          int row = b0 + wm * 64 + rm * 16 + q4 + r;
          int col = n_blk * BN + wn * 64 + cn * 16 + r16;
          size_t off = (size_t)row * OUT_DIM + col;
          out[off] = acc[rm][cn][r] + pa[off] + pb[off];
        }
  }
}

extern "C" void kernel_launch(void* const* d_in, const int* in_sizes, int n_in,
                              void* d_out, int out_size, void* d_ws, size_t ws_size,
                              hipStream_t stream) {
  const float* x = (const float*)d_in[0];
  const float* coeffs = (const float*)d_in[1];
  const float* base_w = (const float*)d_in[2];
  float* out = (float*)d_out;

  uint2* P = (uint2*)d_ws;
  char* Wt = (char*)d_ws + P_BYTES;
  float* part = (float*)((char*)d_ws + P_BYTES + WT_BYTES);
  unsigned* ticket = (unsigned*)((char*)d_ws + P_BYTES + WT_BYTES +
                                 (size_t)KSPLIT * PART_ELEMS * 4);

  pack_fused_kernel<<<PACK_BLKS + WPACK_BLKS, 256, 0, stream>>>(x, P, coeffs, base_w, Wt, ticket);

  if (ws_size >= WS_NEED) {
    kan_gemm<false><<<dim3(B_DIM / BM, OUT_DIM / BN, KSPLIT), 256, 0, stream>>>(P, Wt, part, out, ticket);
  } else {
    zero_out_kernel<<<(int)((PART_ELEMS * 4) / 4096), 256, 0, stream>>>((uint4*)out);
    kan_gemm<true><<<dim3(B_DIM / BM, OUT_DIM / BN, KSPLIT), 256, 0, stream>>>(P, Wt, part, out, ticket);
  }
}

// Round 8
// 190.207 us; speedup vs baseline: 1.6636x; 1.6636x over previous
//
#include <hip/hip_runtime.h>
#include <stdint.h>

// MatrixKAN as dense bf16 MFMA GEMM over expanded interpolation basis.
// Per feature slots [0..20]=hat (2 nonzero), 21=silu(xc) (pairs base_w), 22..23=pad.
// K = 512*24 = 12288. Plane-major LDS tiles (plane = 16B chunk column of 128 rows,
// stride 2048B): conflict-free for linear global_load_lds DMA, lane-linear A
// ds_writes, and 16-row frag reads (R6-verified: SQ_LDS_BANK_CONFLICT = 0).
// BK=96 (4 features, 12 chunks, 3 K32-steps), 48KB LDS -> 3 blocks/CU.
// R8: R6 structure (separate reduce, NO fences/tickets -- R7's in-kernel
// __threadfence reduction stalled the whole device: 244us vs 120us) with
// KSPLIT=3: 768 blocks = exactly 3/CU, one packed round, no ragged tail;
// reduce reads 3 partials (134->100 MB).

typedef short v8s __attribute__((ext_vector_type(8)));
typedef float v4f __attribute__((ext_vector_type(4)));

#define B_DIM 8192
#define IN_DIM 512
#define OUT_DIM 512
#define G_DIM 20
#define FPT 4                        // features per K-tile
#define KT_TOTAL (IN_DIM / FPT)      // 128 K-tiles
#define KSPLIT 3
#define BM 128
#define BN 128
#define CHUNKS 12                    // 16B chunks per tile-row (3 per feature)
#define PLANE 2048                   // 128 rows * 16B per chunk-plane
#define TILE_BYTES (CHUNKS * PLANE)  // 24 KB

#define P_BYTES ((size_t)IN_DIM * B_DIM * 8)                          // 33.55 MB
#define WT_BYTES ((size_t)(OUT_DIM / BN) * KT_TOTAL * TILE_BYTES)     // 12.58 MB
#define PART_ELEMS ((size_t)B_DIM * OUT_DIM)
#define WS_NEED (P_BYTES + WT_BYTES + (size_t)KSPLIT * PART_ELEMS * 4)

#define PACK_BLKS ((B_DIM / 64) * (IN_DIM / 64))   // 1024
#define WPACK_BLKS ((OUT_DIM * IN_DIM) / 256)      // 1024

static __device__ __forceinline__ unsigned f2bf(float f) {
  unsigned u = __builtin_bit_cast(unsigned, f);
  return (u + 0x7fffu + ((u >> 16) & 1u)) >> 16;   // RNE bf16
}

static __device__ __forceinline__ void load16(const void* g, void* l) {
  __builtin_amdgcn_global_load_lds(
      (const __attribute__((address_space(1))) unsigned*)g,
      (__attribute__((address_space(3))) unsigned*)l, 16, 0, 0);
}

__global__ void zero_out_kernel(uint4* __restrict__ out) {
  out[(size_t)blockIdx.x * 256 + threadIdx.x] = uint4{0u, 0u, 0u, 0u};
}

// Fused input-pack. Blocks [0, PACK_BLKS): x[b][i] -> P[i][b] packed
// {.x = bf16(1-t)|bf16(t)<<16, .y = idx|bf16(silu)<<16} via LDS transpose.
// Blocks [PACK_BLKS, +WPACK_BLKS): coeffs/base_w -> Wt plane-major 24KB slabs
// (slab (n_blk,kt): plane 3f+cf = slots 8cf..8cf+7 of feature kt*4+f, row=o&127).
__global__ void pack_fused_kernel(const float* __restrict__ x, uint2* __restrict__ P,
                                  const float* __restrict__ coeffs,
                                  const float* __restrict__ base_w,
                                  char* __restrict__ Wt) {
  __shared__ uint2 tile[64 * 65];
  const int t = threadIdx.x;
  if (blockIdx.x < PACK_BLKS) {
    const int b0 = (blockIdx.x & (B_DIM / 64 - 1)) * 64;
    const int i0 = (blockIdx.x / (B_DIM / 64)) * 64;
    const int tr = t >> 6;
    const int tc = t & 63;
#pragma unroll
    for (int it = 0; it < 16; ++it) {
      int br = it * 4 + tr;
      float xv = x[(size_t)(b0 + br) * IN_DIM + i0 + tc];
      float xc = fminf(fmaxf(xv, -1.0f), 1.0f);
      float xg = (xc + 1.0f) * 10.0f;           // (xc+1)*0.5*G
      int idx = (int)floorf(xg);
      idx = idx < 0 ? 0 : (idx > G_DIM - 1 ? G_DIM - 1 : idx);
      float tt = xg - (float)idx;
      float sl = xc / (1.0f + __expf(-xc));     // silu(clipped x)
      uint2 pv;
      pv.x = f2bf(1.0f - tt) | (f2bf(tt) << 16);
      pv.y = (unsigned)idx | (f2bf(sl) << 16);
      tile[tc * 65 + br] = pv;
    }
    __syncthreads();
#pragma unroll
    for (int it = 0; it < 16; ++it) {
      int ir = it * 4 + tr;
      P[(size_t)(i0 + ir) * B_DIM + b0 + tc] = tile[ir * 65 + tc];
    }
  } else {
    const unsigned u = (blockIdx.x - PACK_BLKS) * 256 + t;
    const int s = u >> 9;            // slab = n_blk*KT_TOTAL + kt
    const int w = u & 511;
    const int row = w >> 2;          // o & 127
    const int f = w & 3;
    const int n_blk = s / KT_TOTAL;
    const int kt = s - n_blk * KT_TOTAL;
    const int o = n_blk * 128 + row;
    const int i = kt * 4 + f;
    const size_t g = (size_t)o * IN_DIM + i;
    const float* c = coeffs + g * 21;
    float cf[21];
#pragma unroll
    for (int j = 0; j < 21; ++j) cf[j] = c[j];
    float bw = base_w[g];
    unsigned d[12];
#pragma unroll
    for (int j = 0; j < 10; ++j) d[j] = f2bf(cf[2 * j]) | (f2bf(cf[2 * j + 1]) << 16);
    d[10] = f2bf(cf[20]) | (f2bf(bw) << 16);  // slots 20, 21(=base_w)
    d[11] = 0u;                               // slots 22,23 pad
    char* slab = Wt + (size_t)s * TILE_BYTES;
#pragma unroll
    for (int p = 0; p < 3; ++p)
      *(uint4*)(slab + (3 * f + p) * PLANE + row * 16) =
          uint4{d[4 * p], d[4 * p + 1], d[4 * p + 2], d[4 * p + 3]};
  }
}

// out = p0+p1+p2 (plain float4 loads -- partials may be L2-resident)
__global__ void reduce_kernel(const v4f* __restrict__ p, v4f* __restrict__ out) {
  size_t i = (size_t)blockIdx.x * 256 + threadIdx.x;
  const size_t q = PART_ELEMS / 4;
  v4f a = p[i], b = p[i + q], c = p[i + 2 * q];
  out[i] = (a + b) + c;
}

// Build one feature's 24-slot strip (12 dwords) in registers, branchless.
// Slots 2q,2q+1 in dword q. Hat: w0 at idx, w1 at idx+1; silu at slot 21.
static __device__ __forceinline__ void build_strip(uint2 pv, unsigned d[12]) {
  const unsigned w0w1 = pv.x;               // idx even, idx==2q: w0|w1<<16
  const unsigned w0hi = pv.x << 16;         // idx odd,  idx==2q+1: w0 at high
  const unsigned w1lo = pv.x >> 16;         // idx+1==2q: w1 at low
  const int idx = (int)(pv.y & 0xffffu);
  const unsigned slhi = pv.y & 0xffff0000u;
#pragma unroll
  for (int q = 0; q <= 10; ++q) {
    unsigned v = 0u;
    v = (idx == 2 * q - 1) ? w1lo : v;
    v = (idx == 2 * q)     ? w0w1 : v;
    v = (idx == 2 * q + 1) ? w0hi : v;
    d[q] = v;
  }
  d[10] |= slhi;
  d[11] = 0u;
}

template <bool ATOMIC>
__global__ __launch_bounds__(256, 3) void kan_gemm(const uint2* __restrict__ P,
                                                   const char* __restrict__ Wt,
                                                   float* __restrict__ dst) {
  __shared__ uint4 lds4[(2 * TILE_BYTES) / 16];   // 24KB A + 24KB B (plane-major)
  char* Ab = (char*)lds4;
  char* Bb = (char*)lds4 + TILE_BYTES;
  const int t = threadIdx.x;
  const int lane = t & 63;
  const int wv = t >> 6;               // 4 waves, 2x2 grid of 64x64 tiles
  const int wm = wv >> 1, wn = wv & 1;
  const int b0 = blockIdx.x * BM;
  const int n_blk = blockIdx.y;
  const int z = blockIdx.z;
  const int kt0 = (z * KT_TOTAL) / KSPLIT;          // 0,42,85
  const int ktend = ((z + 1) * KT_TOTAL) / KSPLIT;  // 42,85,128

  v4f acc[4][4];
  const v4f z4 = {0.f, 0.f, 0.f, 0.f};
#pragma unroll
  for (int ii = 0; ii < 4; ++ii)
#pragma unroll
    for (int jj = 0; jj < 4; ++jj) acc[ii][jj] = z4;

  // A-gen: wave wv owns feature wv (planes 3wv..3wv+2); lane owns rows lane, lane+64
  uint2 pv0 = P[(size_t)(kt0 * 4 + wv) * B_DIM + b0 + lane];
  uint2 pv1 = P[(size_t)(kt0 * 4 + wv) * B_DIM + b0 + lane + 64];

  const int r16 = lane & 15;
  const int q16 = lane >> 4;

  for (int kt = kt0; kt < ktend; ++kt) {
    __syncthreads();   // previous compute done; safe to overwrite tiles

    // B tile: 24KB linear DMA (plane-major slab, lane-linear LDS dst)
    const char* wsrc = Wt + (size_t)(n_blk * KT_TOTAL + kt) * TILE_BYTES;
#pragma unroll
    for (int q = 0; q < 6; ++q)
      load16(wsrc + (q * 256 + t) * 16, Bb + (q * 256 + t) * 16);

    // prefetch next P (in flight across barrier + compute)
    const int ktn = (kt + 1 < ktend) ? kt + 1 : kt;
    uint2 pn0 = P[(size_t)(ktn * 4 + wv) * B_DIM + b0 + lane];
    uint2 pn1 = P[(size_t)(ktn * 4 + wv) * B_DIM + b0 + lane + 64];

    // build + stage 2 A strips: 3x ds_write_b128 each, lane-contiguous per instr
    unsigned d[12];
    build_strip(pv0, d);
#pragma unroll
    for (int p = 0; p < 3; ++p)
      *(uint4*)(Ab + (3 * wv + p) * PLANE + lane * 16) =
          uint4{d[4 * p], d[4 * p + 1], d[4 * p + 2], d[4 * p + 3]};
    build_strip(pv1, d);
#pragma unroll
    for (int p = 0; p < 3; ++p)
      *(uint4*)(Ab + (3 * wv + p) * PLANE + (lane + 64) * 16) =
          uint4{d[4 * p], d[4 * p + 1], d[4 * p + 2], d[4 * p + 3]};
    pv0 = pn0;
    pv1 = pn1;

    __syncthreads();   // drains DMA (vmcnt) + A writes (lgkm)

    // compute: 3 K32-steps, 16 MFMA each per wave
#pragma unroll
    for (int s = 0; s < 3; ++s) {
      const int chunk = s * 4 + q16;   // plane index; k = chunk*8 + j
      v8s af[4], bfr[4];
#pragma unroll
      for (int rm = 0; rm < 4; ++rm) {
        int row = wm * 64 + rm * 16 + r16;
        af[rm] = *(const v8s*)(Ab + chunk * PLANE + row * 16);
      }
#pragma unroll
      for (int cn = 0; cn < 4; ++cn) {
        int row = wn * 64 + cn * 16 + r16;
        bfr[cn] = *(const v8s*)(Bb + chunk * PLANE + row * 16);
      }
#pragma unroll
      for (int rm = 0; rm < 4; ++rm)
#pragma unroll
        for (int cn = 0; cn < 4; ++cn)
          acc[rm][cn] = __builtin_amdgcn_mfma_f32_16x16x32_bf16(af[rm], bfr[cn], acc[rm][cn], 0, 0, 0);
    }
  }

  // epilogue: C/D layout col=lane&15, row=(lane>>4)*4+reg (verified m89/m91)
  float* o = ATOMIC ? dst : dst + (size_t)z * PART_ELEMS;
  const int q4 = (lane >> 4) * 4;
#pragma unroll
  for (int rm = 0; rm < 4; ++rm)
#pragma unroll
    for (int cn = 0; cn < 4; ++cn)
#pragma unroll
      for (int r = 0; r < 4; ++r) {
        int row = b0 + wm * 64 + rm * 16 + q4 + r;
        int col = n_blk * BN + wn * 64 + cn * 16 + r16;
        if (ATOMIC)
          atomicAdd(o + (size_t)row * OUT_DIM + col, acc[rm][cn][r]);
        else
          o[(size_t)row * OUT_DIM + col] = acc[rm][cn][r];
      }
}

extern "C" void kernel_launch(void* const* d_in, const int* in_sizes, int n_in,
                              void* d_out, int out_size, void* d_ws, size_t ws_size,
                              hipStream_t stream) {
  const float* x = (const float*)d_in[0];
  const float* coeffs = (const float*)d_in[1];
  const float* base_w = (const float*)d_in[2];
  float* out = (float*)d_out;

  uint2* P = (uint2*)d_ws;
  char* Wt = (char*)d_ws + P_BYTES;
  float* part = (float*)((char*)d_ws + P_BYTES + WT_BYTES);

  pack_fused_kernel<<<PACK_BLKS + WPACK_BLKS, 256, 0, stream>>>(x, P, coeffs, base_w, Wt);

  if (ws_size >= WS_NEED) {
    kan_gemm<false><<<dim3(B_DIM / BM, OUT_DIM / BN, KSPLIT), 256, 0, stream>>>(P, Wt, part);
    reduce_kernel<<<(int)(PART_ELEMS / 4 / 256), 256, 0, stream>>>((const v4f*)part, (v4f*)out);
  } else {
    zero_out_kernel<<<(int)((PART_ELEMS * 4) / 4096), 256, 0, stream>>>((uint4*)out);
    kan_gemm<true><<<dim3(B_DIM / BM, OUT_DIM / BN, KSPLIT), 256, 0, stream>>>(P, Wt, part);
  }
}

// Round 9
// 189.303 us; speedup vs baseline: 1.6715x; 1.0048x over previous
//
#include <hip/hip_runtime.h>
#include <stdint.h>

// MatrixKAN as dense bf16 MFMA GEMM over expanded interpolation basis.
// Per feature slots [0..20]=hat (2 nonzero), 21=silu(xc) (pairs base_w), 22..23=pad.
// K = 512*24 = 12288. Plane-major LDS tiles (plane = 16B chunk column of 128 rows,
// stride 2048B): conflict-free for linear global_load_lds DMA, lane-linear A
// ds_writes, and 16-row frag reads (R6-verified: SQ_LDS_BANK_CONFLICT = 0).
// BK=96 (4 features, 12 chunks, 3 K32-steps), 48KB LDS -> 3 blocks/CU.
// KSPLIT=3: 768 blocks = exactly 3/CU, one packed round (R8: gemm 104us).
// R9: bf16 split-K partials -- gemm epilogue stores f2bf(acc) (WRITE 49->25MB),
// reduce reads 3 bf16 streams (100->25MB) and writes fp32 out. Partial rounding
// adds ~0.01 absmax on a 0.0625/0.246 margin. No fences (R7 lesson).

typedef short v8s __attribute__((ext_vector_type(8)));
typedef float v4f __attribute__((ext_vector_type(4)));

#define B_DIM 8192
#define IN_DIM 512
#define OUT_DIM 512
#define G_DIM 20
#define FPT 4                        // features per K-tile
#define KT_TOTAL (IN_DIM / FPT)      // 128 K-tiles
#define KSPLIT 3
#define BM 128
#define BN 128
#define CHUNKS 12                    // 16B chunks per tile-row (3 per feature)
#define PLANE 2048                   // 128 rows * 16B per chunk-plane
#define TILE_BYTES (CHUNKS * PLANE)  // 24 KB

#define P_BYTES ((size_t)IN_DIM * B_DIM * 8)                          // 33.55 MB
#define WT_BYTES ((size_t)(OUT_DIM / BN) * KT_TOTAL * TILE_BYTES)     // 12.58 MB
#define PART_ELEMS ((size_t)B_DIM * OUT_DIM)
#define WS_NEED (P_BYTES + WT_BYTES + (size_t)KSPLIT * PART_ELEMS * 2)

#define PACK_BLKS ((B_DIM / 64) * (IN_DIM / 64))   // 1024
#define WPACK_BLKS ((OUT_DIM * IN_DIM) / 256)      // 1024

static __device__ __forceinline__ unsigned f2bf(float f) {
  unsigned u = __builtin_bit_cast(unsigned, f);
  return (u + 0x7fffu + ((u >> 16) & 1u)) >> 16;   // RNE bf16
}

static __device__ __forceinline__ float bflo(unsigned u) {   // bf16 in low 16
  return __builtin_bit_cast(float, u << 16);
}
static __device__ __forceinline__ float bfhi(unsigned u) {   // bf16 in high 16
  return __builtin_bit_cast(float, u & 0xffff0000u);
}

static __device__ __forceinline__ void load16(const void* g, void* l) {
  __builtin_amdgcn_global_load_lds(
      (const __attribute__((address_space(1))) unsigned*)g,
      (__attribute__((address_space(3))) unsigned*)l, 16, 0, 0);
}

__global__ void zero_out_kernel(uint4* __restrict__ out) {
  out[(size_t)blockIdx.x * 256 + threadIdx.x] = uint4{0u, 0u, 0u, 0u};
}

// Fused input-pack. Blocks [0, PACK_BLKS): x[b][i] -> P[i][b] packed
// {.x = bf16(1-t)|bf16(t)<<16, .y = idx|bf16(silu)<<16} via LDS transpose.
// Blocks [PACK_BLKS, +WPACK_BLKS): coeffs/base_w -> Wt plane-major 24KB slabs
// (slab (n_blk,kt): plane 3f+cf = slots 8cf..8cf+7 of feature kt*4+f, row=o&127).
__global__ void pack_fused_kernel(const float* __restrict__ x, uint2* __restrict__ P,
                                  const float* __restrict__ coeffs,
                                  const float* __restrict__ base_w,
                                  char* __restrict__ Wt) {
  __shared__ uint2 tile[64 * 65];
  const int t = threadIdx.x;
  if (blockIdx.x < PACK_BLKS) {
    const int b0 = (blockIdx.x & (B_DIM / 64 - 1)) * 64;
    const int i0 = (blockIdx.x / (B_DIM / 64)) * 64;
    const int tr = t >> 6;
    const int tc = t & 63;
#pragma unroll
    for (int it = 0; it < 16; ++it) {
      int br = it * 4 + tr;
      float xv = x[(size_t)(b0 + br) * IN_DIM + i0 + tc];
      float xc = fminf(fmaxf(xv, -1.0f), 1.0f);
      float xg = (xc + 1.0f) * 10.0f;           // (xc+1)*0.5*G
      int idx = (int)floorf(xg);
      idx = idx < 0 ? 0 : (idx > G_DIM - 1 ? G_DIM - 1 : idx);
      float tt = xg - (float)idx;
      float sl = xc / (1.0f + __expf(-xc));     // silu(clipped x)
      uint2 pv;
      pv.x = f2bf(1.0f - tt) | (f2bf(tt) << 16);
      pv.y = (unsigned)idx | (f2bf(sl) << 16);
      tile[tc * 65 + br] = pv;
    }
    __syncthreads();
#pragma unroll
    for (int it = 0; it < 16; ++it) {
      int ir = it * 4 + tr;
      P[(size_t)(i0 + ir) * B_DIM + b0 + tc] = tile[ir * 65 + tc];
    }
  } else {
    const unsigned u = (blockIdx.x - PACK_BLKS) * 256 + t;
    const int s = u >> 9;            // slab = n_blk*KT_TOTAL + kt
    const int w = u & 511;
    const int row = w >> 2;          // o & 127
    const int f = w & 3;
    const int n_blk = s / KT_TOTAL;
    const int kt = s - n_blk * KT_TOTAL;
    const int o = n_blk * 128 + row;
    const int i = kt * 4 + f;
    const size_t g = (size_t)o * IN_DIM + i;
    const float* c = coeffs + g * 21;
    float cf[21];
#pragma unroll
    for (int j = 0; j < 21; ++j) cf[j] = c[j];
    float bw = base_w[g];
    unsigned d[12];
#pragma unroll
    for (int j = 0; j < 10; ++j) d[j] = f2bf(cf[2 * j]) | (f2bf(cf[2 * j + 1]) << 16);
    d[10] = f2bf(cf[20]) | (f2bf(bw) << 16);  // slots 20, 21(=base_w)
    d[11] = 0u;                               // slots 22,23 pad
    char* slab = Wt + (size_t)s * TILE_BYTES;
#pragma unroll
    for (int p = 0; p < 3; ++p)
      *(uint4*)(slab + (3 * f + p) * PLANE + row * 16) =
          uint4{d[4 * p], d[4 * p + 1], d[4 * p + 2], d[4 * p + 3]};
  }
}

// out = p0+p1+p2: bf16 partial streams (8 per uint4), fp32 accumulate + store.
__global__ void reduce_kernel(const uint4* __restrict__ p, v4f* __restrict__ out) {
  size_t i = (size_t)blockIdx.x * 256 + threadIdx.x;
  const size_t q = PART_ELEMS / 8;
  uint4 a = p[i], b = p[i + q], c = p[i + 2 * q];
  v4f lo, hi;
  lo[0] = bflo(a.x) + bflo(b.x) + bflo(c.x);
  hi[0] = bfhi(a.x) + bfhi(b.x) + bfhi(c.x);
  lo[1] = bflo(a.y) + bflo(b.y) + bflo(c.y);
  hi[1] = bfhi(a.y) + bfhi(b.y) + bfhi(c.y);
  lo[2] = bflo(a.z) + bflo(b.z) + bflo(c.z);
  hi[2] = bfhi(a.z) + bfhi(b.z) + bfhi(c.z);
  lo[3] = bflo(a.w) + bflo(b.w) + bflo(c.w);
  hi[3] = bfhi(a.w) + bfhi(b.w) + bfhi(c.w);
  v4f o0 = {lo[0], hi[0], lo[1], hi[1]};
  v4f o1 = {lo[2], hi[2], lo[3], hi[3]};
  out[2 * i] = o0;
  out[2 * i + 1] = o1;
}

// Build one feature's 24-slot strip (12 dwords) in registers, branchless.
// Slots 2q,2q+1 in dword q. Hat: w0 at idx, w1 at idx+1; silu at slot 21.
static __device__ __forceinline__ void build_strip(uint2 pv, unsigned d[12]) {
  const unsigned w0w1 = pv.x;               // idx even, idx==2q: w0|w1<<16
  const unsigned w0hi = pv.x << 16;         // idx odd,  idx==2q+1: w0 at high
  const unsigned w1lo = pv.x >> 16;         // idx+1==2q: w1 at low
  const int idx = (int)(pv.y & 0xffffu);
  const unsigned slhi = pv.y & 0xffff0000u;
#pragma unroll
  for (int q = 0; q <= 10; ++q) {
    unsigned v = 0u;
    v = (idx == 2 * q - 1) ? w1lo : v;
    v = (idx == 2 * q)     ? w0w1 : v;
    v = (idx == 2 * q + 1) ? w0hi : v;
    d[q] = v;
  }
  d[10] |= slhi;
  d[11] = 0u;
}

template <bool ATOMIC>
__global__ __launch_bounds__(256, 3) void kan_gemm(const uint2* __restrict__ P,
                                                   const char* __restrict__ Wt,
                                                   unsigned short* __restrict__ part,
                                                   float* __restrict__ outA) {
  __shared__ uint4 lds4[(2 * TILE_BYTES) / 16];   // 24KB A + 24KB B (plane-major)
  char* Ab = (char*)lds4;
  char* Bb = (char*)lds4 + TILE_BYTES;
  const int t = threadIdx.x;
  const int lane = t & 63;
  const int wv = t >> 6;               // 4 waves, 2x2 grid of 64x64 tiles
  const int wm = wv >> 1, wn = wv & 1;
  const int b0 = blockIdx.x * BM;
  const int n_blk = blockIdx.y;
  const int z = blockIdx.z;
  const int kt0 = (z * KT_TOTAL) / KSPLIT;          // 0,42,85
  const int ktend = ((z + 1) * KT_TOTAL) / KSPLIT;  // 42,85,128

  v4f acc[4][4];
  const v4f z4 = {0.f, 0.f, 0.f, 0.f};
#pragma unroll
  for (int ii = 0; ii < 4; ++ii)
#pragma unroll
    for (int jj = 0; jj < 4; ++jj) acc[ii][jj] = z4;

  // A-gen: wave wv owns feature wv (planes 3wv..3wv+2); lane owns rows lane, lane+64
  uint2 pv0 = P[(size_t)(kt0 * 4 + wv) * B_DIM + b0 + lane];
  uint2 pv1 = P[(size_t)(kt0 * 4 + wv) * B_DIM + b0 + lane + 64];

  const int r16 = lane & 15;
  const int q16 = lane >> 4;

  for (int kt = kt0; kt < ktend; ++kt) {
    __syncthreads();   // previous compute done; safe to overwrite tiles

    // B tile: 24KB linear DMA (plane-major slab, lane-linear LDS dst)
    const char* wsrc = Wt + (size_t)(n_blk * KT_TOTAL + kt) * TILE_BYTES;
#pragma unroll
    for (int q = 0; q < 6; ++q)
      load16(wsrc + (q * 256 + t) * 16, Bb + (q * 256 + t) * 16);

    // prefetch next P (in flight across barrier + compute)
    const int ktn = (kt + 1 < ktend) ? kt + 1 : kt;
    uint2 pn0 = P[(size_t)(ktn * 4 + wv) * B_DIM + b0 + lane];
    uint2 pn1 = P[(size_t)(ktn * 4 + wv) * B_DIM + b0 + lane + 64];

    // build + stage 2 A strips: 3x ds_write_b128 each, lane-contiguous per instr
    unsigned d[12];
    build_strip(pv0, d);
#pragma unroll
    for (int p = 0; p < 3; ++p)
      *(uint4*)(Ab + (3 * wv + p) * PLANE + lane * 16) =
          uint4{d[4 * p], d[4 * p + 1], d[4 * p + 2], d[4 * p + 3]};
    build_strip(pv1, d);
#pragma unroll
    for (int p = 0; p < 3; ++p)
      *(uint4*)(Ab + (3 * wv + p) * PLANE + (lane + 64) * 16) =
          uint4{d[4 * p], d[4 * p + 1], d[4 * p + 2], d[4 * p + 3]};
    pv0 = pn0;
    pv1 = pn1;

    __syncthreads();   // drains DMA (vmcnt) + A writes (lgkm)

    // compute: 3 K32-steps, 16 MFMA each per wave
#pragma unroll
    for (int s = 0; s < 3; ++s) {
      const int chunk = s * 4 + q16;   // plane index; k = chunk*8 + j
      v8s af[4], bfr[4];
#pragma unroll
      for (int rm = 0; rm < 4; ++rm) {
        int row = wm * 64 + rm * 16 + r16;
        af[rm] = *(const v8s*)(Ab + chunk * PLANE + row * 16);
      }
#pragma unroll
      for (int cn = 0; cn < 4; ++cn) {
        int row = wn * 64 + cn * 16 + r16;
        bfr[cn] = *(const v8s*)(Bb + chunk * PLANE + row * 16);
      }
#pragma unroll
      for (int rm = 0; rm < 4; ++rm)
#pragma unroll
        for (int cn = 0; cn < 4; ++cn)
          acc[rm][cn] = __builtin_amdgcn_mfma_f32_16x16x32_bf16(af[rm], bfr[cn], acc[rm][cn], 0, 0, 0);
    }
  }

  // epilogue: C/D layout col=lane&15, row=(lane>>4)*4+reg (verified m89/m91)
  const int q4 = (lane >> 4) * 4;
  if (ATOMIC) {
#pragma unroll
    for (int rm = 0; rm < 4; ++rm)
#pragma unroll
      for (int cn = 0; cn < 4; ++cn)
#pragma unroll
        for (int r = 0; r < 4; ++r) {
          int row = b0 + wm * 64 + rm * 16 + q4 + r;
          int col = n_blk * BN + wn * 64 + cn * 16 + r16;
          atomicAdd(outA + (size_t)row * OUT_DIM + col, acc[rm][cn][r]);
        }
  } else {
    // bf16 partials: half the split-K write traffic; reduce re-expands to fp32
    unsigned short* mypart = part + (size_t)z * PART_ELEMS;
#pragma unroll
    for (int rm = 0; rm < 4; ++rm)
#pragma unroll
      for (int cn = 0; cn < 4; ++cn)
#pragma unroll
        for (int r = 0; r < 4; ++r) {
          int row = b0 + wm * 64 + rm * 16 + q4 + r;
          int col = n_blk * BN + wn * 64 + cn * 16 + r16;
          mypart[(size_t)row * OUT_DIM + col] = (unsigned short)f2bf(acc[rm][cn][r]);
        }
  }
}

extern "C" void kernel_launch(void* const* d_in, const int* in_sizes, int n_in,
                              void* d_out, int out_size, void* d_ws, size_t ws_size,
                              hipStream_t stream) {
  const float* x = (const float*)d_in[0];
  const float* coeffs = (const float*)d_in[1];
  const float* base_w = (const float*)d_in[2];
  float* out = (float*)d_out;

  uint2* P = (uint2*)d_ws;
  char* Wt = (char*)d_ws + P_BYTES;
  unsigned short* part = (unsigned short*)((char*)d_ws + P_BYTES + WT_BYTES);

  pack_fused_kernel<<<PACK_BLKS + WPACK_BLKS, 256, 0, stream>>>(x, P, coeffs, base_w, Wt);

  if (ws_size >= WS_NEED) {
    kan_gemm<false><<<dim3(B_DIM / BM, OUT_DIM / BN, KSPLIT), 256, 0, stream>>>(P, Wt, part, out);
    reduce_kernel<<<(int)(PART_ELEMS / 8 / 256), 256, 0, stream>>>((const uint4*)part, (v4f*)out);
  } else {
    zero_out_kernel<<<(int)((PART_ELEMS * 4) / 4096), 256, 0, stream>>>((uint4*)out);
    kan_gemm<true><<<dim3(B_DIM / BM, OUT_DIM / BN, KSPLIT), 256, 0, stream>>>(P, Wt, part, out);
  }
}